// Round 9
// baseline (394.226 us; speedup 1.0000x reference)
//
#include <hip/hip_runtime.h>
#include <hip/hip_bf16.h>
#include <math.h>

typedef unsigned short bf16u;
typedef __attribute__((ext_vector_type(8))) short short8;
typedef __attribute__((ext_vector_type(4))) float floatx4;

__device__ __forceinline__ float bf2f(bf16u u) {
  union { unsigned int i; float f; } c;
  c.i = ((unsigned int)u) << 16;
  return c.f;
}
__device__ __forceinline__ bf16u f2bf(float f) {
  union { float f; unsigned int i; } c;
  c.f = f;
  unsigned int lsb = (c.i >> 16) & 1u;
  c.i += 0x7fffu + lsb;
  return (bf16u)(c.i >> 16);
}

__device__ __forceinline__ void load_lds16(const void* g, void* l) {
  __builtin_amdgcn_global_load_lds(
      (const __attribute__((address_space(1))) void*)g,
      (__attribute__((address_space(3))) void*)l, 16, 0, 0);
}

// ---------------------------------------------------------------- LayerNorm
__global__ __launch_bounds__(256) void ln_kernel(
    const float* __restrict__ x, bf16u* __restrict__ out,
    const float* __restrict__ gamma, const float* __restrict__ beta) {
  const int row = blockIdx.x;
  const int tid = threadIdx.x;
  const int lane = tid & 63, wave = tid >> 6;
  __shared__ float red[4];
  const float* xr = x + (size_t)row * 1024;
  float v[4];
#pragma unroll
  for (int i = 0; i < 4; i++) v[i] = xr[tid + i * 256];
  float s = v[0] + v[1] + v[2] + v[3];
#pragma unroll
  for (int off = 32; off; off >>= 1) s += __shfl_down(s, off);
  if (lane == 0) red[wave] = s;
  __syncthreads();
  const float mean = (red[0] + red[1] + red[2] + red[3]) * (1.0f / 1024.0f);
  __syncthreads();
  float sq = 0.f;
#pragma unroll
  for (int i = 0; i < 4; i++) { float d = v[i] - mean; sq += d * d; }
#pragma unroll
  for (int off = 32; off; off >>= 1) sq += __shfl_down(sq, off);
  if (lane == 0) red[wave] = sq;
  __syncthreads();
  const float var = (red[0] + red[1] + red[2] + red[3]) * (1.0f / 1023.0f);
  const float inv = 1.0f / (sqrtf(var) + 1e-8f);
  bf16u* orow = out + (size_t)row * 1024;
#pragma unroll
  for (int i = 0; i < 4; i++) {
    int idx = tid + i * 256;
    orow[idx] = f2bf((v[i] - mean) * inv * gamma[idx] + beta[idx]);
  }
}

// ---------------------------------------------------------------- Weight pack
// All six fp32->bf16 weight transposes in ONE launch (flat blockIdx.x decode,
// block-uniform branching). out[c*R + r] = (bf16)in[r*C + c].
__global__ __launch_bounds__(256) void pack_weights(
    const float* __restrict__ wq, const float* __restrict__ wk,
    const float* __restrict__ wv, const float* __restrict__ wo,
    const float* __restrict__ w1, const float* __restrict__ w2,
    bf16u* __restrict__ WqkvT, bf16u* __restrict__ woT,
    bf16u* __restrict__ w1T, bf16u* __restrict__ w2T) {
  __shared__ bf16u tile[32][33];
  const int id = blockIdx.x;
  const float* in; bf16u* out; int R, C, bx, by;
  if (id < 3072) {            // wq/wk/wv: 16 heads x (1024 x 64)
    int job = id >> 10, rem = id & 1023;
    int head = rem >> 6, t = rem & 63;
    bx = t & 1; by = t >> 1;
    in = (job == 0 ? wq : (job == 1 ? wk : wv)) + head * 65536;
    out = WqkvT + job * 1048576 + head * 65536;
    R = 1024; C = 64;
  } else if (id < 4096) {     // wo: 1024 x 1024
    int rem = id - 3072; bx = rem & 31; by = rem >> 5;
    in = wo; out = woT; R = 1024; C = 1024;
  } else if (id < 8192) {     // w1: 1024 x 4096
    int rem = id - 4096; bx = rem & 127; by = rem >> 7;
    in = w1; out = w1T; R = 1024; C = 4096;
  } else {                    // w2: 4096 x 1024
    int rem = id - 8192; bx = rem & 31; by = rem >> 5;
    in = w2; out = w2T; R = 4096; C = 1024;
  }
  const int bc = bx * 32, br = by * 32;
  const int lx = threadIdx.x & 31, ly = threadIdx.x >> 5;
#pragma unroll
  for (int i = 0; i < 32; i += 8)
    tile[ly + i][lx] = f2bf(in[(size_t)(br + ly + i) * C + bc + lx]);
  __syncthreads();
#pragma unroll
  for (int i = 0; i < 32; i += 8)
    out[(size_t)(bc + ly + i) * R + br + lx] = tile[lx][ly + i];
}

// bf16 -> bf16 transpose (for V inside QKV).
__global__ __launch_bounds__(256) void transpose_b(
    const bf16u* __restrict__ in, bf16u* __restrict__ out,
    int ins, int coff, int outs) {
  __shared__ bf16u tile[32][33];
  const int bc = blockIdx.x * 32, br = blockIdx.y * 32;
  const int lx = threadIdx.x & 31, ly = threadIdx.x >> 5;
#pragma unroll
  for (int i = 0; i < 32; i += 8)
    tile[ly + i][lx] = in[(size_t)(br + ly + i) * ins + coff + bc + lx];
  __syncthreads();
#pragma unroll
  for (int i = 0; i < 32; i += 8)
    out[(size_t)(bc + ly + i) * outs + br + lx] = tile[lx][ly + i];
}

// ---------------------------------------------------------------- GEMM (B^T)
// C[M,N] = A[M,K] @ Bt[N,K]^T, bf16 in, fp32 accumulate, async LDS staging.
// BK=128: half the barrier/vmcnt drains per K vs BK=64 (GEMMs are
// iteration-drain bound at low occupancy — round-3/8 evidence).
// EPI: 0 = store bf16; 1 = +bias +f32 residual -> f32; 2 = +bias, GELU -> bf16;
//      3 = raw f32 partial at Cout + z*M*N (split-K)
template <int BM, int BN, int BK, int WGR, int WGC, int EPI>
__global__ __launch_bounds__(256, (BN == 128 ? 2 : 4)) void gemm_bt(
    const bf16u* __restrict__ A, const bf16u* __restrict__ Bt,
    const float* __restrict__ bias, const float* __restrict__ res,
    void* __restrict__ Cout, int M, int N, int K, int kchunk) {
  constexpr int TM = BM / WGR, TN = BN / WGC;
  constexpr int NI = TM / 16, NJ = TN / 16;
  constexpr int CPR = BK / 8;  // 16B chunks per row
  alignas(16) __shared__ bf16u sA[BM * BK];
  alignas(16) __shared__ bf16u sB[BN * BK];
  const int tid = threadIdx.x, lane = tid & 63, wave = tid >> 6;
  const int wr = wave / WGC, wc = wave % WGC;
  const int quad = lane >> 4, l16 = lane & 15;
  const int m0 = blockIdx.y * BM, n0 = blockIdx.x * BN;
  const int kz = blockIdx.z;
  const int kbeg = kz * kchunk;
  const int kend = (kbeg + kchunk < K) ? (kbeg + kchunk) : K;

  floatx4 acc[NI][NJ] = {};
  constexpr int ACH = BM * BK / 8;
  constexpr int BCH = BN * BK / 8;

  for (int k0 = kbeg; k0 < kend; k0 += BK) {
#pragma unroll
    for (int c = tid; c < ACH; c += 256) {
      int r = c / CPR, kc = (c % CPR) * 8;
      load_lds16(A + (size_t)(m0 + r) * K + k0 + kc, (void*)(sA + c * 8));
    }
#pragma unroll
    for (int c = tid; c < BCH; c += 256) {
      int r = c / CPR, kc = (c % CPR) * 8;
      load_lds16(Bt + (size_t)(n0 + r) * K + k0 + kc, (void*)(sB + c * 8));
    }
    __syncthreads();
#pragma unroll
    for (int kk = 0; kk < BK; kk += 32) {
      const int kq = kk + quad * 8;
      short8 af[NI], bf[NJ];
#pragma unroll
      for (int i = 0; i < NI; i++)
        af[i] = *(const short8*)(sA + (wr * TM + i * 16 + l16) * BK + kq);
#pragma unroll
      for (int j = 0; j < NJ; j++)
        bf[j] = *(const short8*)(sB + (wc * TN + j * 16 + l16) * BK + kq);
#pragma unroll
      for (int i = 0; i < NI; i++)
#pragma unroll
        for (int j = 0; j < NJ; j++)
          acc[i][j] = __builtin_amdgcn_mfma_f32_16x16x32_bf16(af[i], bf[j], acc[i][j], 0, 0, 0);
    }
    __syncthreads();
  }

  float* pout = (float*)Cout;
  if constexpr (EPI == 3) pout += (size_t)kz * M * N;
#pragma unroll
  for (int j = 0; j < NJ; j++) {
    const int col = n0 + wc * TN + j * 16 + l16;
    float bv = 0.0f;
    if constexpr (EPI == 1 || EPI == 2) bv = bias[col];
#pragma unroll
    for (int i = 0; i < NI; i++) {
#pragma unroll
      for (int r = 0; r < 4; r++) {
        const int row = m0 + wr * TM + i * 16 + quad * 4 + r;
        const size_t o = (size_t)row * N + col;
        const float v = acc[i][j][r];
        if constexpr (EPI == 0) {
          ((bf16u*)Cout)[o] = f2bf(v);
        } else if constexpr (EPI == 1) {
          pout[o] = v + bv + res[o];
        } else if constexpr (EPI == 2) {
          float t = v + bv;
          ((bf16u*)Cout)[o] = f2bf(0.5f * t * (1.0f + erff(t * 0.70710678118654752f)));
        } else {
          pout[o] = v;
        }
      }
    }
  }
}

// ---------------------------------------------------------------- split-K reduce
__global__ __launch_bounds__(256) void reduce2_kernel(
    const float* __restrict__ part, const float* __restrict__ bias,
    const float* __restrict__ res, float* __restrict__ out,
    int N, size_t total) {
  size_t i = ((size_t)blockIdx.x * 256 + threadIdx.x) * 4;
  if (i >= total) return;
  float4 a = *(const float4*)(part + i);
  float4 b = *(const float4*)(part + total + i);
  float4 r = *(const float4*)(res + i);
  float4 bv = *(const float4*)(bias + (int)(i & (size_t)(N - 1)));
  float4 o;
  o.x = a.x + b.x + r.x + bv.x;
  o.y = a.y + b.y + r.y + bv.y;
  o.z = a.z + b.z + r.z + bv.z;
  o.w = a.w + b.w + r.w + bv.w;
  *(float4*)(out + i) = o;
}

// ---------------------------------------------------------------- Flash attention
// (frozen from round 8 — three variants all plateau at 73-75 us)
template <int NT>
__device__ __forceinline__ void attn_tile(
    const bf16u* sQ, const bf16u* sK, const bf16u* sVt, bf16u* sP,
    floatx4* aco, floatx4& acc_l, short8 ones,
    int q0, int c0, int wave, int quad, int l16) {
  constexpr int SK = 72, SV = 136;
  floatx4 s[NT] = {};
#pragma unroll
  for (int kk = 0; kk < 64; kk += 32) {
    short8 aq = *(const short8*)(sQ + (wave * 16 + l16) * SK + kk + quad * 8);
#pragma unroll
    for (int nt = 0; nt < NT; nt++) {
      short8 bk = *(const short8*)(sK + (nt * 16 + l16) * SK + kk + quad * 8);
      s[nt] = __builtin_amdgcn_mfma_f32_16x16x32_bf16(bk, aq, s[nt], 0, 0, 0);
    }
  }
  const float C = 0.125f * 1.44269504088896f;  // 1/sqrt(64) * log2(e)
  const int qrow = q0 + wave * 16 + l16;
#pragma unroll
  for (int nt = 0; nt < NT; nt++)
#pragma unroll
    for (int r = 0; r < 4; r++) {
      const int kpos = c0 + nt * 16 + quad * 4 + r;
      float t = s[nt][r] * C;
      if (kpos > qrow) t = -__builtin_inff();
      s[nt][r] = __builtin_amdgcn_exp2f(t);
    }
  __syncthreads();  // all waves done reading sK before sP overwrite
#pragma unroll
  for (int nt = 0; nt < NT; nt++) {
    unsigned int lo = (unsigned int)f2bf(s[nt][0]) | ((unsigned int)f2bf(s[nt][1]) << 16);
    unsigned int hi = (unsigned int)f2bf(s[nt][2]) | ((unsigned int)f2bf(s[nt][3]) << 16);
    uint2 pk; pk.x = lo; pk.y = hi;
    *(uint2*)(sP + (wave * 16 + l16) * SV + nt * 16 + quad * 4) = pk;
  }
  __syncthreads();  // sP fully written
#pragma unroll
  for (int kk = 0; kk < NT * 16; kk += 32) {
    short8 ap = *(const short8*)(sP + (wave * 16 + l16) * SV + kk + quad * 8);
#pragma unroll
    for (int dt = 0; dt < 4; dt++) {
      short8 bv = *(const short8*)(sVt + (dt * 16 + l16) * SV + kk + quad * 8);
      aco[dt] = __builtin_amdgcn_mfma_f32_16x16x32_bf16(ap, bv, aco[dt], 0, 0, 0);
    }
    acc_l = __builtin_amdgcn_mfma_f32_16x16x32_bf16(ap, ones, acc_l, 0, 0, 0);
  }
}

__global__ __launch_bounds__(256, 3) void flash_attn(
    const bf16u* __restrict__ QKV, const bf16u* __restrict__ Vt,
    bf16u* __restrict__ ctx) {
  const int qb = 31 - blockIdx.x;  // longest-job-first
  const int h = blockIdx.y;
  const int tid = threadIdx.x, lane = tid & 63, wave = tid >> 6;
  const int quad = lane >> 4, l16 = lane & 15;
  constexpr int SK = 72, SV = 136;
  alignas(16) __shared__ bf16u sQ[64 * SK];
  alignas(16) __shared__ bf16u sK[128 * SK];   // overlaid by sP (17408 B)
  alignas(16) __shared__ bf16u sVt[64 * SV];   // [dim][pos]
  bf16u* sP = sK;                              // [qrow][kpos]
  const int q0 = qb * 64;

  for (int c = tid; c < 512; c += 256) {
    int r = c >> 3, e8 = (c & 7) * 8;
    *(uint4*)(sQ + r * SK + e8) =
        *(const uint4*)(QKV + (size_t)(q0 + r) * 3072 + h * 64 + e8);
  }

  floatx4 acc_l = {0.f, 0.f, 0.f, 0.f};
  floatx4 aco[4] = {};
  short8 ones;
#pragma unroll
  for (int u = 0; u < 8; u++) ones[u] = (short)0x3F80;  // bf16 1.0

  const int nkt = (qb >> 1) + 1;  // 128-wide K tiles
  for (int kt = 0; kt < nkt; kt++) {
    const int c0 = kt * 128;
    __syncthreads();  // prev PV reads of sP(=sK)/sVt done
    for (int c = tid; c < 1024; c += 256) {
      int r = c >> 3, e8 = (c & 7) * 8;
      *(uint4*)(sK + r * SK + e8) =
          *(const uint4*)(QKV + (size_t)(c0 + r) * 3072 + 1024 + h * 64 + e8);
    }
    for (int c = tid; c < 1024; c += 256) {
      int e = c >> 4, s8 = (c & 15) * 8;
      *(uint4*)(sVt + e * SV + s8) =
          *(const uint4*)(Vt + (size_t)(h * 64 + e) * 2048 + c0 + s8);
    }
    __syncthreads();
    if (kt == nkt - 1 && (qb & 1) == 0)
      attn_tile<4>(sQ, sK, sVt, sP, aco, acc_l, ones, q0, c0, wave, quad, l16);
    else
      attn_tile<8>(sQ, sK, sVt, sP, aco, acc_l, ones, q0, c0, wave, quad, l16);
  }
#pragma unroll
  for (int dt = 0; dt < 4; dt++)
#pragma unroll
    for (int r = 0; r < 4; r++) {
      int t = q0 + wave * 16 + quad * 4 + r;
      ctx[(size_t)t * 1024 + h * 64 + dt * 16 + l16] = f2bf(aco[dt][r] / acc_l[r]);
    }
}

// ---------------------------------------------------------------- launch
extern "C" void kernel_launch(void* const* d_in, const int* in_sizes, int n_in,
                              void* d_out, int out_size, void* d_ws, size_t ws_size,
                              hipStream_t stream) {
  (void)in_sizes; (void)n_in; (void)out_size; (void)ws_size;
  const float* x   = (const float*)d_in[0];
  const float* wq  = (const float*)d_in[1];
  const float* wk  = (const float*)d_in[2];
  const float* wv  = (const float*)d_in[3];
  const float* wo  = (const float*)d_in[4];
  const float* bo  = (const float*)d_in[5];
  const float* g1  = (const float*)d_in[6];
  const float* be1 = (const float*)d_in[7];
  const float* g2  = (const float*)d_in[8];
  const float* be2 = (const float*)d_in[9];
  const float* w1  = (const float*)d_in[10];
  const float* bb1 = (const float*)d_in[11];
  const float* w2  = (const float*)d_in[12];
  const float* bb2 = (const float*)d_in[13];

  char* p = (char*)d_ws;
  const size_t MB = 1024 * 1024;
  bf16u* WqkvT = (bf16u*)(p + 0 * MB);    //  6 MB, dead after QKV gemm
  bf16u* woT   = (bf16u*)(p + 6 * MB);    //  2 MB, dead after wo gemm
  bf16u* w1T   = (bf16u*)(p + 8 * MB);    //  8 MB, dead after FFN1
  bf16u* w2T   = (bf16u*)(p + 16 * MB);   //  8 MB
  bf16u* hln   = (bf16u*)(p + 24 * MB);   //  4 MB, reused as h2 / Vtr
  bf16u* QKV   = (bf16u*)(p + 28 * MB);   // 12 MB, dead after attn
  bf16u* ctx   = (bf16u*)(p + 40 * MB);   //  4 MB, dead after wo gemm
  float* x1    = (float*)(p + 44 * MB);   //  8 MB, live to end
  bf16u* mid   = (bf16u*)(p + 28 * MB);   // 16 MB, overlays QKV+ctx
  float* part  = (float*)(p + 0 * MB);    // 16 MB, overlays weight packs
  bf16u* Vtr   = hln;                     //  4 MB (1024 x 2048)
  bf16u* h2    = hln;

  // all six weight packs (fp32 -> bf16, N x K layout) in one launch
  pack_weights<<<12288, 256, 0, stream>>>(wq, wk, wv, wo, w1, w2,
                                          WqkvT, woT, w1T, w2T);

  // h = LN1(x); QKV = h @ [wq|wk|wv]   (64x128 tiles, BK=128 -> 8 K-iters)
  ln_kernel<<<2048, 256, 0, stream>>>(x, hln, g1, be1);
  gemm_bt<64, 128, 128, 2, 2, 0><<<dim3(24, 32, 1), 256, 0, stream>>>(
      hln, WqkvT, nullptr, nullptr, QKV, 2048, 3072, 1024, 1024);
  // Vtr[c][t] = V[t][c]
  transpose_b<<<dim3(32, 64), 256, 0, stream>>>(QKV, Vtr, 3072, 2048, 2048);
  // ctx = causal softmax(Q K^T / 8) V
  flash_attn<<<dim3(32, 16), 256, 0, stream>>>(QKV, Vtr, ctx);
  // x1 = x + ctx @ wo + bo (fp32); 32x64, BK=128 -> 8 K-iters, 1024 blocks
  gemm_bt<32, 64, 128, 2, 2, 1><<<dim3(16, 64, 1), 256, 0, stream>>>(
      ctx, woT, bo, x, x1, 2048, 1024, 1024, 1024);
  // h2 = LN2(x1); mid = gelu(h2 @ w1 + b1)  (64x128, BK=128, 1024 blocks)
  ln_kernel<<<2048, 256, 0, stream>>>(x1, h2, g2, be2);
  gemm_bt<64, 128, 128, 2, 2, 2><<<dim3(32, 32, 1), 256, 0, stream>>>(
      h2, w1T, bb1, nullptr, mid, 2048, 4096, 1024, 1024);
  // out = x1 + mid @ w2 + b2 : 64x64 BK=128 split-K=2 -> 16 iters, 1024 blocks
  gemm_bt<64, 64, 128, 2, 2, 3><<<dim3(16, 32, 2), 256, 0, stream>>>(
      mid, w2T, nullptr, nullptr, part, 2048, 1024, 4096, 2048);
  reduce2_kernel<<<2048, 256, 0, stream>>>(part, bb2, x1, (float*)d_out,
                                           1024, (size_t)2048 * 1024);
}

// Round 10
// 296.815 us; speedup vs baseline: 1.3282x; 1.3282x over previous
//
#include <hip/hip_runtime.h>
#include <hip/hip_bf16.h>
#include <math.h>

typedef unsigned short bf16u;
typedef __attribute__((ext_vector_type(8))) short short8;
typedef __attribute__((ext_vector_type(4))) float floatx4;

__device__ __forceinline__ float bf2f(bf16u u) {
  union { unsigned int i; float f; } c;
  c.i = ((unsigned int)u) << 16;
  return c.f;
}
__device__ __forceinline__ bf16u f2bf(float f) {
  union { float f; unsigned int i; } c;
  c.f = f;
  unsigned int lsb = (c.i >> 16) & 1u;
  c.i += 0x7fffu + lsb;
  return (bf16u)(c.i >> 16);
}

__device__ __forceinline__ void load_lds16(const void* g, void* l) {
  __builtin_amdgcn_global_load_lds(
      (const __attribute__((address_space(1))) void*)g,
      (__attribute__((address_space(3))) void*)l, 16, 0, 0);
}

// ---------------------------------------------------------------- LayerNorm
__global__ __launch_bounds__(256) void ln_kernel(
    const float* __restrict__ x, bf16u* __restrict__ out,
    const float* __restrict__ gamma, const float* __restrict__ beta) {
  const int row = blockIdx.x;
  const int tid = threadIdx.x;
  const int lane = tid & 63, wave = tid >> 6;
  __shared__ float red[4];
  const float* xr = x + (size_t)row * 1024;
  float v[4];
#pragma unroll
  for (int i = 0; i < 4; i++) v[i] = xr[tid + i * 256];
  float s = v[0] + v[1] + v[2] + v[3];
#pragma unroll
  for (int off = 32; off; off >>= 1) s += __shfl_down(s, off);
  if (lane == 0) red[wave] = s;
  __syncthreads();
  const float mean = (red[0] + red[1] + red[2] + red[3]) * (1.0f / 1024.0f);
  __syncthreads();
  float sq = 0.f;
#pragma unroll
  for (int i = 0; i < 4; i++) { float d = v[i] - mean; sq += d * d; }
#pragma unroll
  for (int off = 32; off; off >>= 1) sq += __shfl_down(sq, off);
  if (lane == 0) red[wave] = sq;
  __syncthreads();
  const float var = (red[0] + red[1] + red[2] + red[3]) * (1.0f / 1023.0f);
  const float inv = 1.0f / (sqrtf(var) + 1e-8f);
  bf16u* orow = out + (size_t)row * 1024;
#pragma unroll
  for (int i = 0; i < 4; i++) {
    int idx = tid + i * 256;
    orow[idx] = f2bf((v[i] - mean) * inv * gamma[idx] + beta[idx]);
  }
}

// ---------------------------------------------------------------- Weight pack
// All six fp32->bf16 weight transposes in ONE launch.
__global__ __launch_bounds__(256) void pack_weights(
    const float* __restrict__ wq, const float* __restrict__ wk,
    const float* __restrict__ wv, const float* __restrict__ wo,
    const float* __restrict__ w1, const float* __restrict__ w2,
    bf16u* __restrict__ WqkvT, bf16u* __restrict__ woT,
    bf16u* __restrict__ w1T, bf16u* __restrict__ w2T) {
  __shared__ bf16u tile[32][33];
  const int id = blockIdx.x;
  const float* in; bf16u* out; int R, C, bx, by;
  if (id < 3072) {            // wq/wk/wv: 16 heads x (1024 x 64)
    int job = id >> 10, rem = id & 1023;
    int head = rem >> 6, t = rem & 63;
    bx = t & 1; by = t >> 1;
    in = (job == 0 ? wq : (job == 1 ? wk : wv)) + head * 65536;
    out = WqkvT + job * 1048576 + head * 65536;
    R = 1024; C = 64;
  } else if (id < 4096) {     // wo: 1024 x 1024
    int rem = id - 3072; bx = rem & 31; by = rem >> 5;
    in = wo; out = woT; R = 1024; C = 1024;
  } else if (id < 8192) {     // w1: 1024 x 4096
    int rem = id - 4096; bx = rem & 127; by = rem >> 7;
    in = w1; out = w1T; R = 1024; C = 4096;
  } else {                    // w2: 4096 x 1024
    int rem = id - 8192; bx = rem & 31; by = rem >> 5;
    in = w2; out = w2T; R = 4096; C = 1024;
  }
  const int bc = bx * 32, br = by * 32;
  const int lx = threadIdx.x & 31, ly = threadIdx.x >> 5;
#pragma unroll
  for (int i = 0; i < 32; i += 8)
    tile[ly + i][lx] = f2bf(in[(size_t)(br + ly + i) * C + bc + lx]);
  __syncthreads();
#pragma unroll
  for (int i = 0; i < 32; i += 8)
    out[(size_t)(bc + ly + i) * R + br + lx] = tile[lx][ly + i];
}

// bf16 -> bf16 transpose (for V inside QKV).
__global__ __launch_bounds__(256) void transpose_b(
    const bf16u* __restrict__ in, bf16u* __restrict__ out,
    int ins, int coff, int outs) {
  __shared__ bf16u tile[32][33];
  const int bc = blockIdx.x * 32, br = blockIdx.y * 32;
  const int lx = threadIdx.x & 31, ly = threadIdx.x >> 5;
#pragma unroll
  for (int i = 0; i < 32; i += 8)
    tile[ly + i][lx] = in[(size_t)(br + ly + i) * ins + coff + bc + lx];
  __syncthreads();
#pragma unroll
  for (int i = 0; i < 32; i += 8)
    out[(size_t)(bc + ly + i) * outs + br + lx] = tile[lx][ly + i];
}

// ---------------------------------------------------------------- GEMM (B^T)
// C[M,N] = A[M,K] @ Bt[N,K]^T, bf16 in, fp32 accumulate, BK=64.
// XOR-SWIZZLED LDS: slot s of row r holds global chunk s^(r&7). Staging
// permutes the GLOBAL address per lane (global_load_lds LDS side must stay
// linear — m104); fragment reads use slot ch^(R&7), spreading the 16 l16
// lanes across all 8 bank groups -> 2-way aliasing (free, m136) instead of
// the structural 16-way conflict of the unswizzled layout (round-9 post-
// mortem: 2.2e7 conflict cycles; round-3: 9.4e6).
// EPI: 0 = store bf16; 1 = +bias +f32 residual -> f32; 2 = +bias, GELU -> bf16;
//      3 = raw f32 partial at Cout + z*M*N (split-K)
template <int BM, int BN, int WGR, int WGC, int EPI>
__global__ __launch_bounds__(256, (BN == 128 ? 2 : 4)) void gemm_bt(
    const bf16u* __restrict__ A, const bf16u* __restrict__ Bt,
    const float* __restrict__ bias, const float* __restrict__ res,
    void* __restrict__ Cout, int M, int N, int K, int kchunk) {
  constexpr int BK = 64;
  constexpr int TM = BM / WGR, TN = BN / WGC;
  constexpr int NI = TM / 16, NJ = TN / 16;
  alignas(16) __shared__ bf16u sA[BM * BK];
  alignas(16) __shared__ bf16u sB[BN * BK];
  const int tid = threadIdx.x, lane = tid & 63, wave = tid >> 6;
  const int wr = wave / WGC, wc = wave % WGC;
  const int quad = lane >> 4, l16 = lane & 15;
  const int m0 = blockIdx.y * BM, n0 = blockIdx.x * BN;
  const int kz = blockIdx.z;
  const int kbeg = kz * kchunk;
  const int kend = (kbeg + kchunk < K) ? (kbeg + kchunk) : K;

  floatx4 acc[NI][NJ] = {};
  constexpr int ACH = BM * BK / 8;
  constexpr int BCH = BN * BK / 8;

  for (int k0 = kbeg; k0 < kend; k0 += BK) {
#pragma unroll
    for (int c = tid; c < ACH; c += 256) {
      int r = c >> 3, kc = ((c ^ r) & 7) * 8;  // swizzled source chunk
      load_lds16(A + (size_t)(m0 + r) * K + k0 + kc, (void*)(sA + c * 8));
    }
#pragma unroll
    for (int c = tid; c < BCH; c += 256) {
      int r = c >> 3, kc = ((c ^ r) & 7) * 8;
      load_lds16(Bt + (size_t)(n0 + r) * K + k0 + kc, (void*)(sB + c * 8));
    }
    __syncthreads();
#pragma unroll
    for (int kk = 0; kk < BK; kk += 32) {
      const int ch = (kk >> 3) + quad;  // global chunk wanted
      short8 af[NI], bf[NJ];
#pragma unroll
      for (int i = 0; i < NI; i++) {
        const int R = wr * TM + i * 16 + l16;
        af[i] = *(const short8*)(sA + R * BK + ((ch ^ (R & 7)) << 3));
      }
#pragma unroll
      for (int j = 0; j < NJ; j++) {
        const int R = wc * TN + j * 16 + l16;
        bf[j] = *(const short8*)(sB + R * BK + ((ch ^ (R & 7)) << 3));
      }
#pragma unroll
      for (int i = 0; i < NI; i++)
#pragma unroll
        for (int j = 0; j < NJ; j++)
          acc[i][j] = __builtin_amdgcn_mfma_f32_16x16x32_bf16(af[i], bf[j], acc[i][j], 0, 0, 0);
    }
    __syncthreads();
  }

  float* pout = (float*)Cout;
  if constexpr (EPI == 3) pout += (size_t)kz * M * N;
#pragma unroll
  for (int j = 0; j < NJ; j++) {
    const int col = n0 + wc * TN + j * 16 + l16;
    float bv = 0.0f;
    if constexpr (EPI == 1 || EPI == 2) bv = bias[col];
#pragma unroll
    for (int i = 0; i < NI; i++) {
#pragma unroll
      for (int r = 0; r < 4; r++) {
        const int row = m0 + wr * TM + i * 16 + quad * 4 + r;
        const size_t o = (size_t)row * N + col;
        const float v = acc[i][j][r];
        if constexpr (EPI == 0) {
          ((bf16u*)Cout)[o] = f2bf(v);
        } else if constexpr (EPI == 1) {
          pout[o] = v + bv + res[o];
        } else if constexpr (EPI == 2) {
          float t = v + bv;
          ((bf16u*)Cout)[o] = f2bf(0.5f * t * (1.0f + erff(t * 0.70710678118654752f)));
        } else {
          pout[o] = v;
        }
      }
    }
  }
}

// ---------------------------------------------------------------- split-K reduce
__global__ __launch_bounds__(256) void reduce2_kernel(
    const float* __restrict__ part, const float* __restrict__ bias,
    const float* __restrict__ res, float* __restrict__ out,
    int N, size_t total) {
  size_t i = ((size_t)blockIdx.x * 256 + threadIdx.x) * 4;
  if (i >= total) return;
  float4 a = *(const float4*)(part + i);
  float4 b = *(const float4*)(part + total + i);
  float4 r = *(const float4*)(res + i);
  float4 bv = *(const float4*)(bias + (int)(i & (size_t)(N - 1)));
  float4 o;
  o.x = a.x + b.x + r.x + bv.x;
  o.y = a.y + b.y + r.y + bv.y;
  o.z = a.z + b.z + r.z + bv.z;
  o.w = a.w + b.w + r.w + bv.w;
  *(float4*)(out + i) = o;
}

// ---------------------------------------------------------------- Flash attention
// (frozen from round 8)
template <int NT>
__device__ __forceinline__ void attn_tile(
    const bf16u* sQ, const bf16u* sK, const bf16u* sVt, bf16u* sP,
    floatx4* aco, floatx4& acc_l, short8 ones,
    int q0, int c0, int wave, int quad, int l16) {
  constexpr int SK = 72, SV = 136;
  floatx4 s[NT] = {};
#pragma unroll
  for (int kk = 0; kk < 64; kk += 32) {
    short8 aq = *(const short8*)(sQ + (wave * 16 + l16) * SK + kk + quad * 8);
#pragma unroll
    for (int nt = 0; nt < NT; nt++) {
      short8 bk = *(const short8*)(sK + (nt * 16 + l16) * SK + kk + quad * 8);
      s[nt] = __builtin_amdgcn_mfma_f32_16x16x32_bf16(bk, aq, s[nt], 0, 0, 0);
    }
  }
  const float C = 0.125f * 1.44269504088896f;  // 1/sqrt(64) * log2(e)
  const int qrow = q0 + wave * 16 + l16;
#pragma unroll
  for (int nt = 0; nt < NT; nt++)
#pragma unroll
    for (int r = 0; r < 4; r++) {
      const int kpos = c0 + nt * 16 + quad * 4 + r;
      float t = s[nt][r] * C;
      if (kpos > qrow) t = -__builtin_inff();
      s[nt][r] = __builtin_amdgcn_exp2f(t);
    }
  __syncthreads();  // all waves done reading sK before sP overwrite
#pragma unroll
  for (int nt = 0; nt < NT; nt++) {
    unsigned int lo = (unsigned int)f2bf(s[nt][0]) | ((unsigned int)f2bf(s[nt][1]) << 16);
    unsigned int hi = (unsigned int)f2bf(s[nt][2]) | ((unsigned int)f2bf(s[nt][3]) << 16);
    uint2 pk; pk.x = lo; pk.y = hi;
    *(uint2*)(sP + (wave * 16 + l16) * SV + nt * 16 + quad * 4) = pk;
  }
  __syncthreads();  // sP fully written
#pragma unroll
  for (int kk = 0; kk < NT * 16; kk += 32) {
    short8 ap = *(const short8*)(sP + (wave * 16 + l16) * SV + kk + quad * 8);
#pragma unroll
    for (int dt = 0; dt < 4; dt++) {
      short8 bv = *(const short8*)(sVt + (dt * 16 + l16) * SV + kk + quad * 8);
      aco[dt] = __builtin_amdgcn_mfma_f32_16x16x32_bf16(ap, bv, aco[dt], 0, 0, 0);
    }
    acc_l = __builtin_amdgcn_mfma_f32_16x16x32_bf16(ap, ones, acc_l, 0, 0, 0);
  }
}

__global__ __launch_bounds__(256, 3) void flash_attn(
    const bf16u* __restrict__ QKV, const bf16u* __restrict__ Vt,
    bf16u* __restrict__ ctx) {
  const int qb = 31 - blockIdx.x;  // longest-job-first
  const int h = blockIdx.y;
  const int tid = threadIdx.x, lane = tid & 63, wave = tid >> 6;
  const int quad = lane >> 4, l16 = lane & 15;
  constexpr int SK = 72, SV = 136;
  alignas(16) __shared__ bf16u sQ[64 * SK];
  alignas(16) __shared__ bf16u sK[128 * SK];   // overlaid by sP (17408 B)
  alignas(16) __shared__ bf16u sVt[64 * SV];   // [dim][pos]
  bf16u* sP = sK;                              // [qrow][kpos]
  const int q0 = qb * 64;

  for (int c = tid; c < 512; c += 256) {
    int r = c >> 3, e8 = (c & 7) * 8;
    *(uint4*)(sQ + r * SK + e8) =
        *(const uint4*)(QKV + (size_t)(q0 + r) * 3072 + h * 64 + e8);
  }

  floatx4 acc_l = {0.f, 0.f, 0.f, 0.f};
  floatx4 aco[4] = {};
  short8 ones;
#pragma unroll
  for (int u = 0; u < 8; u++) ones[u] = (short)0x3F80;  // bf16 1.0

  const int nkt = (qb >> 1) + 1;  // 128-wide K tiles
  for (int kt = 0; kt < nkt; kt++) {
    const int c0 = kt * 128;
    __syncthreads();  // prev PV reads of sP(=sK)/sVt done
    for (int c = tid; c < 1024; c += 256) {
      int r = c >> 3, e8 = (c & 7) * 8;
      *(uint4*)(sK + r * SK + e8) =
          *(const uint4*)(QKV + (size_t)(c0 + r) * 3072 + 1024 + h * 64 + e8);
    }
    for (int c = tid; c < 1024; c += 256) {
      int e = c >> 4, s8 = (c & 15) * 8;
      *(uint4*)(sVt + e * SV + s8) =
          *(const uint4*)(Vt + (size_t)(h * 64 + e) * 2048 + c0 + s8);
    }
    __syncthreads();
    if (kt == nkt - 1 && (qb & 1) == 0)
      attn_tile<4>(sQ, sK, sVt, sP, aco, acc_l, ones, q0, c0, wave, quad, l16);
    else
      attn_tile<8>(sQ, sK, sVt, sP, aco, acc_l, ones, q0, c0, wave, quad, l16);
  }
#pragma unroll
  for (int dt = 0; dt < 4; dt++)
#pragma unroll
    for (int r = 0; r < 4; r++) {
      int t = q0 + wave * 16 + quad * 4 + r;
      ctx[(size_t)t * 1024 + h * 64 + dt * 16 + l16] = f2bf(aco[dt][r] / acc_l[r]);
    }
}

// ---------------------------------------------------------------- launch
extern "C" void kernel_launch(void* const* d_in, const int* in_sizes, int n_in,
                              void* d_out, int out_size, void* d_ws, size_t ws_size,
                              hipStream_t stream) {
  (void)in_sizes; (void)n_in; (void)out_size; (void)ws_size;
  const float* x   = (const float*)d_in[0];
  const float* wq  = (const float*)d_in[1];
  const float* wk  = (const float*)d_in[2];
  const float* wv  = (const float*)d_in[3];
  const float* wo  = (const float*)d_in[4];
  const float* bo  = (const float*)d_in[5];
  const float* g1  = (const float*)d_in[6];
  const float* be1 = (const float*)d_in[7];
  const float* g2  = (const float*)d_in[8];
  const float* be2 = (const float*)d_in[9];
  const float* w1  = (const float*)d_in[10];
  const float* bb1 = (const float*)d_in[11];
  const float* w2  = (const float*)d_in[12];
  const float* bb2 = (const float*)d_in[13];

  char* p = (char*)d_ws;
  const size_t MB = 1024 * 1024;
  bf16u* WqkvT = (bf16u*)(p + 0 * MB);    //  6 MB, dead after QKV gemm
  bf16u* woT   = (bf16u*)(p + 6 * MB);    //  2 MB, dead after wo gemm
  bf16u* w1T   = (bf16u*)(p + 8 * MB);    //  8 MB, dead after FFN1
  bf16u* w2T   = (bf16u*)(p + 16 * MB);   //  8 MB
  bf16u* hln   = (bf16u*)(p + 24 * MB);   //  4 MB, reused as h2 / Vtr
  bf16u* QKV   = (bf16u*)(p + 28 * MB);   // 12 MB, dead after attn
  bf16u* ctx   = (bf16u*)(p + 40 * MB);   //  4 MB, dead after wo gemm
  float* x1    = (float*)(p + 44 * MB);   //  8 MB, live to end
  bf16u* mid   = (bf16u*)(p + 28 * MB);   // 16 MB, overlays QKV+ctx
  float* part  = (float*)(p + 0 * MB);    // 16 MB, overlays weight packs
  bf16u* Vtr   = hln;                     //  4 MB (1024 x 2048)
  bf16u* h2    = hln;

  // all six weight packs (fp32 -> bf16, N x K layout) in one launch
  pack_weights<<<12288, 256, 0, stream>>>(wq, wk, wv, wo, w1, w2,
                                          WqkvT, woT, w1T, w2T);

  // h = LN1(x); QKV = h @ [wq|wk|wv]   (64x128 tiles, BK=64)
  ln_kernel<<<2048, 256, 0, stream>>>(x, hln, g1, be1);
  gemm_bt<64, 128, 2, 2, 0><<<dim3(24, 32, 1), 256, 0, stream>>>(
      hln, WqkvT, nullptr, nullptr, QKV, 2048, 3072, 1024, 1024);
  // Vtr[c][t] = V[t][c]
  transpose_b<<<dim3(32, 64), 256, 0, stream>>>(QKV, Vtr, 3072, 2048, 2048);
  // ctx = causal softmax(Q K^T / 8) V
  flash_attn<<<dim3(32, 16), 256, 0, stream>>>(QKV, Vtr, ctx);
  // x1 = x + ctx @ wo + bo (fp32); 32x64 tiles -> 1024 blocks
  gemm_bt<32, 64, 2, 2, 1><<<dim3(16, 64, 1), 256, 0, stream>>>(
      ctx, woT, bo, x, x1, 2048, 1024, 1024, 1024);
  // h2 = LN2(x1); mid = gelu(h2 @ w1 + b1)  (64x128 tiles -> 1024 blocks)
  ln_kernel<<<2048, 256, 0, stream>>>(x1, h2, g2, be2);
  gemm_bt<64, 128, 2, 2, 2><<<dim3(32, 32, 1), 256, 0, stream>>>(
      h2, w1T, bb1, nullptr, mid, 2048, 4096, 1024, 1024);
  // out = x1 + mid @ w2 + b2 : 64x64 split-K=2 -> 1024 blocks
  gemm_bt<64, 64, 2, 2, 3><<<dim3(16, 32, 2), 256, 0, stream>>>(
      mid, w2T, nullptr, nullptr, part, 2048, 1024, 4096, 2048);
  reduce2_kernel<<<2048, 256, 0, stream>>>(part, bb2, x1, (float*)d_out,
                                           1024, (size_t)2048 * 1024);
}

// Round 11
// 288.588 us; speedup vs baseline: 1.3661x; 1.0285x over previous
//
#include <hip/hip_runtime.h>
#include <hip/hip_bf16.h>
#include <math.h>

typedef unsigned short bf16u;
typedef __attribute__((ext_vector_type(8))) short short8;
typedef __attribute__((ext_vector_type(4))) float floatx4;

__device__ __forceinline__ float bf2f(bf16u u) {
  union { unsigned int i; float f; } c;
  c.i = ((unsigned int)u) << 16;
  return c.f;
}
__device__ __forceinline__ bf16u f2bf(float f) {
  union { float f; unsigned int i; } c;
  c.f = f;
  unsigned int lsb = (c.i >> 16) & 1u;
  c.i += 0x7fffu + lsb;
  return (bf16u)(c.i >> 16);
}

__device__ __forceinline__ void load_lds16(const void* g, void* l) {
  __builtin_amdgcn_global_load_lds(
      (const __attribute__((address_space(1))) void*)g,
      (__attribute__((address_space(3))) void*)l, 16, 0, 0);
}

// ---------------------------------------------------------------- LayerNorm
__global__ __launch_bounds__(256) void ln_kernel(
    const float* __restrict__ x, bf16u* __restrict__ out,
    const float* __restrict__ gamma, const float* __restrict__ beta) {
  const int row = blockIdx.x;
  const int tid = threadIdx.x;
  const int lane = tid & 63, wave = tid >> 6;
  __shared__ float red[4];
  const float* xr = x + (size_t)row * 1024;
  float v[4];
#pragma unroll
  for (int i = 0; i < 4; i++) v[i] = xr[tid + i * 256];
  float s = v[0] + v[1] + v[2] + v[3];
#pragma unroll
  for (int off = 32; off; off >>= 1) s += __shfl_down(s, off);
  if (lane == 0) red[wave] = s;
  __syncthreads();
  const float mean = (red[0] + red[1] + red[2] + red[3]) * (1.0f / 1024.0f);
  __syncthreads();
  float sq = 0.f;
#pragma unroll
  for (int i = 0; i < 4; i++) { float d = v[i] - mean; sq += d * d; }
#pragma unroll
  for (int off = 32; off; off >>= 1) sq += __shfl_down(sq, off);
  if (lane == 0) red[wave] = sq;
  __syncthreads();
  const float var = (red[0] + red[1] + red[2] + red[3]) * (1.0f / 1023.0f);
  const float inv = 1.0f / (sqrtf(var) + 1e-8f);
  bf16u* orow = out + (size_t)row * 1024;
#pragma unroll
  for (int i = 0; i < 4; i++) {
    int idx = tid + i * 256;
    orow[idx] = f2bf((v[i] - mean) * inv * gamma[idx] + beta[idx]);
  }
}

// ---------------------------------------------------------------- Weight pack
__global__ __launch_bounds__(256) void pack_weights(
    const float* __restrict__ wq, const float* __restrict__ wk,
    const float* __restrict__ wv, const float* __restrict__ wo,
    const float* __restrict__ w1, const float* __restrict__ w2,
    bf16u* __restrict__ WqkvT, bf16u* __restrict__ woT,
    bf16u* __restrict__ w1T, bf16u* __restrict__ w2T) {
  __shared__ bf16u tile[32][33];
  const int id = blockIdx.x;
  const float* in; bf16u* out; int R, C, bx, by;
  if (id < 3072) {            // wq/wk/wv: 16 heads x (1024 x 64)
    int job = id >> 10, rem = id & 1023;
    int head = rem >> 6, t = rem & 63;
    bx = t & 1; by = t >> 1;
    in = (job == 0 ? wq : (job == 1 ? wk : wv)) + head * 65536;
    out = WqkvT + job * 1048576 + head * 65536;
    R = 1024; C = 64;
  } else if (id < 4096) {     // wo: 1024 x 1024
    int rem = id - 3072; bx = rem & 31; by = rem >> 5;
    in = wo; out = woT; R = 1024; C = 1024;
  } else if (id < 8192) {     // w1: 1024 x 4096
    int rem = id - 4096; bx = rem & 127; by = rem >> 7;
    in = w1; out = w1T; R = 1024; C = 4096;
  } else {                    // w2: 4096 x 1024
    int rem = id - 8192; bx = rem & 31; by = rem >> 5;
    in = w2; out = w2T; R = 4096; C = 1024;
  }
  const int bc = bx * 32, br = by * 32;
  const int lx = threadIdx.x & 31, ly = threadIdx.x >> 5;
#pragma unroll
  for (int i = 0; i < 32; i += 8)
    tile[ly + i][lx] = f2bf(in[(size_t)(br + ly + i) * C + bc + lx]);
  __syncthreads();
#pragma unroll
  for (int i = 0; i < 32; i += 8)
    out[(size_t)(bc + ly + i) * R + br + lx] = tile[lx][ly + i];
}

// bf16 -> bf16 transpose (for V inside QKV).
__global__ __launch_bounds__(256) void transpose_b(
    const bf16u* __restrict__ in, bf16u* __restrict__ out,
    int ins, int coff, int outs) {
  __shared__ bf16u tile[32][33];
  const int bc = blockIdx.x * 32, br = blockIdx.y * 32;
  const int lx = threadIdx.x & 31, ly = threadIdx.x >> 5;
#pragma unroll
  for (int i = 0; i < 32; i += 8)
    tile[ly + i][lx] = in[(size_t)(br + ly + i) * ins + coff + bc + lx];
  __syncthreads();
#pragma unroll
  for (int i = 0; i < 32; i += 8)
    out[(size_t)(bc + ly + i) * outs + br + lx] = tile[lx][ly + i];
}

// ---------------------------------------------------------------- GEMM (B^T)
// XOR-swizzled LDS (round-10: kills the structural 16-way ds_read conflict).
template <int BM, int BN, int WGR, int WGC, int EPI>
__global__ __launch_bounds__(256, (BN == 128 ? 2 : 4)) void gemm_bt(
    const bf16u* __restrict__ A, const bf16u* __restrict__ Bt,
    const float* __restrict__ bias, const float* __restrict__ res,
    void* __restrict__ Cout, int M, int N, int K, int kchunk) {
  constexpr int BK = 64;
  constexpr int TM = BM / WGR, TN = BN / WGC;
  constexpr int NI = TM / 16, NJ = TN / 16;
  alignas(16) __shared__ bf16u sA[BM * BK];
  alignas(16) __shared__ bf16u sB[BN * BK];
  const int tid = threadIdx.x, lane = tid & 63, wave = tid >> 6;
  const int wr = wave / WGC, wc = wave % WGC;
  const int quad = lane >> 4, l16 = lane & 15;
  const int m0 = blockIdx.y * BM, n0 = blockIdx.x * BN;
  const int kz = blockIdx.z;
  const int kbeg = kz * kchunk;
  const int kend = (kbeg + kchunk < K) ? (kbeg + kchunk) : K;

  floatx4 acc[NI][NJ] = {};
  constexpr int ACH = BM * BK / 8;
  constexpr int BCH = BN * BK / 8;

  for (int k0 = kbeg; k0 < kend; k0 += BK) {
#pragma unroll
    for (int c = tid; c < ACH; c += 256) {
      int r = c >> 3, kc = ((c ^ r) & 7) * 8;  // swizzled source chunk
      load_lds16(A + (size_t)(m0 + r) * K + k0 + kc, (void*)(sA + c * 8));
    }
#pragma unroll
    for (int c = tid; c < BCH; c += 256) {
      int r = c >> 3, kc = ((c ^ r) & 7) * 8;
      load_lds16(Bt + (size_t)(n0 + r) * K + k0 + kc, (void*)(sB + c * 8));
    }
    __syncthreads();
#pragma unroll
    for (int kk = 0; kk < BK; kk += 32) {
      const int ch = (kk >> 3) + quad;
      short8 af[NI], bf[NJ];
#pragma unroll
      for (int i = 0; i < NI; i++) {
        const int R = wr * TM + i * 16 + l16;
        af[i] = *(const short8*)(sA + R * BK + ((ch ^ (R & 7)) << 3));
      }
#pragma unroll
      for (int j = 0; j < NJ; j++) {
        const int R = wc * TN + j * 16 + l16;
        bf[j] = *(const short8*)(sB + R * BK + ((ch ^ (R & 7)) << 3));
      }
#pragma unroll
      for (int i = 0; i < NI; i++)
#pragma unroll
        for (int j = 0; j < NJ; j++)
          acc[i][j] = __builtin_amdgcn_mfma_f32_16x16x32_bf16(af[i], bf[j], acc[i][j], 0, 0, 0);
    }
    __syncthreads();
  }

  float* pout = (float*)Cout;
  if constexpr (EPI == 3) pout += (size_t)kz * M * N;
#pragma unroll
  for (int j = 0; j < NJ; j++) {
    const int col = n0 + wc * TN + j * 16 + l16;
    float bv = 0.0f;
    if constexpr (EPI == 1 || EPI == 2) bv = bias[col];
#pragma unroll
    for (int i = 0; i < NI; i++) {
#pragma unroll
      for (int r = 0; r < 4; r++) {
        const int row = m0 + wr * TM + i * 16 + quad * 4 + r;
        const size_t o = (size_t)row * N + col;
        const float v = acc[i][j][r];
        if constexpr (EPI == 0) {
          ((bf16u*)Cout)[o] = f2bf(v);
        } else if constexpr (EPI == 1) {
          pout[o] = v + bv + res[o];
        } else if constexpr (EPI == 2) {
          float t = v + bv;
          ((bf16u*)Cout)[o] = f2bf(0.5f * t * (1.0f + erff(t * 0.70710678118654752f)));
        } else {
          pout[o] = v;
        }
      }
    }
  }
}

// ---------------------------------------------------------------- split-K reduce (FFN2)
__global__ __launch_bounds__(256) void reduce2_kernel(
    const float* __restrict__ part, const float* __restrict__ bias,
    const float* __restrict__ res, float* __restrict__ out,
    int N, size_t total) {
  size_t i = ((size_t)blockIdx.x * 256 + threadIdx.x) * 4;
  if (i >= total) return;
  float4 a = *(const float4*)(part + i);
  float4 b = *(const float4*)(part + total + i);
  float4 r = *(const float4*)(res + i);
  float4 bv = *(const float4*)(bias + (int)(i & (size_t)(N - 1)));
  float4 o;
  o.x = a.x + b.x + r.x + bv.x;
  o.y = a.y + b.y + r.y + bv.y;
  o.z = a.z + b.z + r.z + bv.z;
  o.w = a.w + b.w + r.w + bv.w;
  *(float4*)(out + i) = o;
}

// ---------------------------------------------------------------- Flash attention
// Fixed-max softmax => O and l are PURE SUMS over key tiles => split-K
// across NZ blocks (strided kt) with a trivial combine pass. No rescaling,
// no running max. Tile math identical to round 8 (template<NT>, all bounds
// compile-time).
template <int NT>
__device__ __forceinline__ void attn_tile(
    const bf16u* sQ, const bf16u* sK, const bf16u* sVt, bf16u* sP,
    floatx4* aco, floatx4& acc_l, short8 ones,
    int q0, int c0, int wave, int quad, int l16) {
  constexpr int SK = 72, SV = 136;
  floatx4 s[NT] = {};
#pragma unroll
  for (int kk = 0; kk < 64; kk += 32) {
    short8 aq = *(const short8*)(sQ + (wave * 16 + l16) * SK + kk + quad * 8);
#pragma unroll
    for (int nt = 0; nt < NT; nt++) {
      short8 bk = *(const short8*)(sK + (nt * 16 + l16) * SK + kk + quad * 8);
      s[nt] = __builtin_amdgcn_mfma_f32_16x16x32_bf16(bk, aq, s[nt], 0, 0, 0);
    }
  }
  const float C = 0.125f * 1.44269504088896f;  // 1/sqrt(64) * log2(e)
  const int qrow = q0 + wave * 16 + l16;
#pragma unroll
  for (int nt = 0; nt < NT; nt++)
#pragma unroll
    for (int r = 0; r < 4; r++) {
      const int kpos = c0 + nt * 16 + quad * 4 + r;
      float t = s[nt][r] * C;
      if (kpos > qrow) t = -__builtin_inff();
      s[nt][r] = __builtin_amdgcn_exp2f(t);
    }
  __syncthreads();  // all waves done reading sK before sP overwrite
#pragma unroll
  for (int nt = 0; nt < NT; nt++) {
    unsigned int lo = (unsigned int)f2bf(s[nt][0]) | ((unsigned int)f2bf(s[nt][1]) << 16);
    unsigned int hi = (unsigned int)f2bf(s[nt][2]) | ((unsigned int)f2bf(s[nt][3]) << 16);
    uint2 pk; pk.x = lo; pk.y = hi;
    *(uint2*)(sP + (wave * 16 + l16) * SV + nt * 16 + quad * 4) = pk;
  }
  __syncthreads();  // sP fully written
#pragma unroll
  for (int kk = 0; kk < NT * 16; kk += 32) {
    short8 ap = *(const short8*)(sP + (wave * 16 + l16) * SV + kk + quad * 8);
#pragma unroll
    for (int dt = 0; dt < 4; dt++) {
      short8 bv = *(const short8*)(sVt + (dt * 16 + l16) * SV + kk + quad * 8);
      aco[dt] = __builtin_amdgcn_mfma_f32_16x16x32_bf16(ap, bv, aco[dt], 0, 0, 0);
    }
    acc_l = __builtin_amdgcn_mfma_f32_16x16x32_bf16(ap, ones, acc_l, 0, 0, 0);
  }
}

template <int NZ>
__global__ __launch_bounds__(256, 3) void flash_attn(
    const bf16u* __restrict__ QKV, const bf16u* __restrict__ Vt,
    bf16u* __restrict__ partO, float* __restrict__ partL) {
  const int qb = 31 - blockIdx.x;
  const int h = blockIdx.y;
  const int z = blockIdx.z;
  const int tid = threadIdx.x, lane = tid & 63, wave = tid >> 6;
  const int quad = lane >> 4, l16 = lane & 15;
  constexpr int SK = 72, SV = 136;
  alignas(16) __shared__ bf16u sQ[64 * SK];
  alignas(16) __shared__ bf16u sK[128 * SK];   // overlaid by sP
  alignas(16) __shared__ bf16u sVt[64 * SV];
  bf16u* sP = sK;
  const int q0 = qb * 64;

  for (int c = tid; c < 512; c += 256) {
    int r = c >> 3, e8 = (c & 7) * 8;
    *(uint4*)(sQ + r * SK + e8) =
        *(const uint4*)(QKV + (size_t)(q0 + r) * 3072 + h * 64 + e8);
  }

  floatx4 acc_l = {0.f, 0.f, 0.f, 0.f};
  floatx4 aco[4] = {};
  short8 ones;
#pragma unroll
  for (int u = 0; u < 8; u++) ones[u] = (short)0x3F80;  // bf16 1.0

  const int nkt = (qb >> 1) + 1;  // 128-wide K tiles
  for (int kt = z; kt < nkt; kt += NZ) {
    const int c0 = kt * 128;
    __syncthreads();
    for (int c = tid; c < 1024; c += 256) {
      int r = c >> 3, e8 = (c & 7) * 8;
      *(uint4*)(sK + r * SK + e8) =
          *(const uint4*)(QKV + (size_t)(c0 + r) * 3072 + 1024 + h * 64 + e8);
    }
    for (int c = tid; c < 1024; c += 256) {
      int e = c >> 4, s8 = (c & 15) * 8;
      *(uint4*)(sVt + e * SV + s8) =
          *(const uint4*)(Vt + (size_t)(h * 64 + e) * 2048 + c0 + s8);
    }
    __syncthreads();
    if (kt == nkt - 1 && (qb & 1) == 0)
      attn_tile<4>(sQ, sK, sVt, sP, aco, acc_l, ones, q0, c0, wave, quad, l16);
    else
      attn_tile<8>(sQ, sK, sVt, sP, aco, acc_l, ones, q0, c0, wave, quad, l16);
  }
  // write partials (zero-iteration blocks write zeros — every slot covered once)
  bf16u* po = partO + ((size_t)z * 2048 + q0) * 1024 + h * 64;
#pragma unroll
  for (int dt = 0; dt < 4; dt++)
#pragma unroll
    for (int r = 0; r < 4; r++)
      po[(wave * 16 + quad * 4 + r) * 1024 + dt * 16 + l16] = f2bf(aco[dt][r]);
  if (l16 == 0) {
#pragma unroll
    for (int r = 0; r < 4; r++)
      partL[((size_t)z * 2048 + q0 + wave * 16 + quad * 4 + r) * 16 + h] = acc_l[r];
  }
}

// combine: ctx[t][col] = sum_z O_z / sum_z l_z
template <int NZ>
__global__ __launch_bounds__(256) void attn_reduce(
    const bf16u* __restrict__ partO, const float* __restrict__ partL,
    bf16u* __restrict__ ctx) {
  const int t = blockIdx.x;
  const int col = threadIdx.x * 4;
  const int h = col >> 6;
  float l = 0.f;
#pragma unroll
  for (int z = 0; z < NZ; z++) l += partL[((size_t)z * 2048 + t) * 16 + h];
  float o0 = 0.f, o1 = 0.f, o2 = 0.f, o3 = 0.f;
#pragma unroll
  for (int z = 0; z < NZ; z++) {
    uint2 v = *(const uint2*)(partO + ((size_t)z * 2048 + t) * 1024 + col);
    o0 += bf2f((bf16u)(v.x & 0xffff)); o1 += bf2f((bf16u)(v.x >> 16));
    o2 += bf2f((bf16u)(v.y & 0xffff)); o3 += bf2f((bf16u)(v.y >> 16));
  }
  const float inv = 1.0f / l;
  uint2 pk;
  pk.x = (unsigned int)f2bf(o0 * inv) | ((unsigned int)f2bf(o1 * inv) << 16);
  pk.y = (unsigned int)f2bf(o2 * inv) | ((unsigned int)f2bf(o3 * inv) << 16);
  *(uint2*)(ctx + (size_t)t * 1024 + col) = pk;
}

// ---------------------------------------------------------------- launch
extern "C" void kernel_launch(void* const* d_in, const int* in_sizes, int n_in,
                              void* d_out, int out_size, void* d_ws, size_t ws_size,
                              hipStream_t stream) {
  (void)in_sizes; (void)n_in; (void)out_size; (void)ws_size;
  const float* x   = (const float*)d_in[0];
  const float* wq  = (const float*)d_in[1];
  const float* wk  = (const float*)d_in[2];
  const float* wv  = (const float*)d_in[3];
  const float* wo  = (const float*)d_in[4];
  const float* bo  = (const float*)d_in[5];
  const float* g1  = (const float*)d_in[6];
  const float* be1 = (const float*)d_in[7];
  const float* g2  = (const float*)d_in[8];
  const float* be2 = (const float*)d_in[9];
  const float* w1  = (const float*)d_in[10];
  const float* bb1 = (const float*)d_in[11];
  const float* w2  = (const float*)d_in[12];
  const float* bb2 = (const float*)d_in[13];

  // workspace layout by liveness (peak 57 MB):
  //  [0,6)   WqkvT      dead after QKV gemm
  //  [6,8)   woT        dead after wo gemm
  //  [8,16)  w1T        dead after FFN1
  //  [16,24) w2T        dead after FFN2
  //  [24,28) multi slot: hln -> Vtr -> ctx -> h2 (strictly sequential)
  //  [28,40) QKV        dead after flash  | mid [28,44) from FFN1
  //  [40,41) partL      dead after attn_reduce
  //  [41,57) partO      dead after attn_reduce | x1 [49,57) from wo gemm
  //  [0,16)  partFFN (fp32) from FFN2 (packs dead by then)
  char* p = (char*)d_ws;
  const size_t MB = 1024 * 1024;
  constexpr int NZ = 4;
  bf16u* WqkvT = (bf16u*)(p + 0 * MB);
  bf16u* woT   = (bf16u*)(p + 6 * MB);
  bf16u* w1T   = (bf16u*)(p + 8 * MB);
  bf16u* w2T   = (bf16u*)(p + 16 * MB);
  bf16u* multi = (bf16u*)(p + 24 * MB);   // hln / Vtr / ctx / h2
  bf16u* QKV   = (bf16u*)(p + 28 * MB);
  float* partL = (float*)(p + 40 * MB);
  bf16u* partO = (bf16u*)(p + 41 * MB);
  bf16u* mid   = (bf16u*)(p + 28 * MB);
  float* x1    = (float*)(p + 49 * MB);
  float* partF = (float*)(p + 0 * MB);
  bf16u* hln = multi, *Vtr = multi, *ctx = multi, *h2 = multi;

  pack_weights<<<12288, 256, 0, stream>>>(wq, wk, wv, wo, w1, w2,
                                          WqkvT, woT, w1T, w2T);

  // h = LN1(x); QKV = h @ [wq|wk|wv]
  ln_kernel<<<2048, 256, 0, stream>>>(x, hln, g1, be1);
  gemm_bt<64, 128, 2, 2, 0><<<dim3(24, 32, 1), 256, 0, stream>>>(
      hln, WqkvT, nullptr, nullptr, QKV, 2048, 3072, 1024, 1024);
  // Vtr[c][t] = V[t][c]
  transpose_b<<<dim3(32, 64), 256, 0, stream>>>(QKV, Vtr, 3072, 2048, 2048);
  // split-K flash attention (2048 balanced blocks) + combine
  flash_attn<NZ><<<dim3(32, 16, NZ), 256, 0, stream>>>(QKV, Vtr, partO, partL);
  attn_reduce<NZ><<<2048, 256, 0, stream>>>(partO, partL, ctx);
  // x1 = x + ctx @ wo + bo (fp32)
  gemm_bt<32, 64, 2, 2, 1><<<dim3(16, 64, 1), 256, 0, stream>>>(
      ctx, woT, bo, x, x1, 2048, 1024, 1024, 1024);
  // h2 = LN2(x1); mid = gelu(h2 @ w1 + b1)
  ln_kernel<<<2048, 256, 0, stream>>>(x1, h2, g2, be2);
  gemm_bt<64, 128, 2, 2, 2><<<dim3(32, 32, 1), 256, 0, stream>>>(
      h2, w1T, bb1, nullptr, mid, 2048, 4096, 1024, 1024);
  // out = x1 + mid @ w2 + b2 : split-K=2 + fused reduce
  gemm_bt<64, 64, 2, 2, 3><<<dim3(16, 32, 2), 256, 0, stream>>>(
      mid, w2T, nullptr, nullptr, partF, 2048, 1024, 4096, 2048);
  reduce2_kernel<<<2048, 256, 0, stream>>>(partF, bb2, x1, (float*)d_out,
                                           1024, (size_t)2048 * 1024);
}

// Round 12
// 272.159 us; speedup vs baseline: 1.4485x; 1.0604x over previous
//
#include <hip/hip_runtime.h>
#include <hip/hip_bf16.h>
#include <math.h>

typedef unsigned short bf16u;
typedef __attribute__((ext_vector_type(8))) short short8;
typedef __attribute__((ext_vector_type(4))) float floatx4;

__device__ __forceinline__ float bf2f(bf16u u) {
  union { unsigned int i; float f; } c;
  c.i = ((unsigned int)u) << 16;
  return c.f;
}
__device__ __forceinline__ bf16u f2bf(float f) {
  union { float f; unsigned int i; } c;
  c.f = f;
  unsigned int lsb = (c.i >> 16) & 1u;
  c.i += 0x7fffu + lsb;
  return (bf16u)(c.i >> 16);
}

__device__ __forceinline__ void load_lds16(const void* g, void* l) {
  __builtin_amdgcn_global_load_lds(
      (const __attribute__((address_space(1))) void*)g,
      (__attribute__((address_space(3))) void*)l, 16, 0, 0);
}

// ---------------------------------------------------------------- LayerNorm
__global__ __launch_bounds__(256) void ln_kernel(
    const float* __restrict__ x, bf16u* __restrict__ out,
    const float* __restrict__ gamma, const float* __restrict__ beta) {
  const int row = blockIdx.x;
  const int tid = threadIdx.x;
  const int lane = tid & 63, wave = tid >> 6;
  __shared__ float red[4];
  const float* xr = x + (size_t)row * 1024;
  float v[4];
#pragma unroll
  for (int i = 0; i < 4; i++) v[i] = xr[tid + i * 256];
  float s = v[0] + v[1] + v[2] + v[3];
#pragma unroll
  for (int off = 32; off; off >>= 1) s += __shfl_down(s, off);
  if (lane == 0) red[wave] = s;
  __syncthreads();
  const float mean = (red[0] + red[1] + red[2] + red[3]) * (1.0f / 1024.0f);
  __syncthreads();
  float sq = 0.f;
#pragma unroll
  for (int i = 0; i < 4; i++) { float d = v[i] - mean; sq += d * d; }
#pragma unroll
  for (int off = 32; off; off >>= 1) sq += __shfl_down(sq, off);
  if (lane == 0) red[wave] = sq;
  __syncthreads();
  const float var = (red[0] + red[1] + red[2] + red[3]) * (1.0f / 1023.0f);
  const float inv = 1.0f / (sqrtf(var) + 1e-8f);
  bf16u* orow = out + (size_t)row * 1024;
#pragma unroll
  for (int i = 0; i < 4; i++) {
    int idx = tid + i * 256;
    orow[idx] = f2bf((v[i] - mean) * inv * gamma[idx] + beta[idx]);
  }
}

// ---------------------------------------------------------------- Weight pack
__global__ __launch_bounds__(256) void pack_weights(
    const float* __restrict__ wq, const float* __restrict__ wk,
    const float* __restrict__ wv, const float* __restrict__ wo,
    const float* __restrict__ w1, const float* __restrict__ w2,
    bf16u* __restrict__ WqkvT, bf16u* __restrict__ woT,
    bf16u* __restrict__ w1T, bf16u* __restrict__ w2T) {
  __shared__ bf16u tile[32][33];
  const int id = blockIdx.x;
  const float* in; bf16u* out; int R, C, bx, by;
  if (id < 3072) {            // wq/wk/wv: 16 heads x (1024 x 64)
    int job = id >> 10, rem = id & 1023;
    int head = rem >> 6, t = rem & 63;
    bx = t & 1; by = t >> 1;
    in = (job == 0 ? wq : (job == 1 ? wk : wv)) + head * 65536;
    out = WqkvT + job * 1048576 + head * 65536;
    R = 1024; C = 64;
  } else if (id < 4096) {     // wo: 1024 x 1024
    int rem = id - 3072; bx = rem & 31; by = rem >> 5;
    in = wo; out = woT; R = 1024; C = 1024;
  } else if (id < 8192) {     // w1: 1024 x 4096
    int rem = id - 4096; bx = rem & 127; by = rem >> 7;
    in = w1; out = w1T; R = 1024; C = 4096;
  } else {                    // w2: 4096 x 1024
    int rem = id - 8192; bx = rem & 31; by = rem >> 5;
    in = w2; out = w2T; R = 4096; C = 1024;
  }
  const int bc = bx * 32, br = by * 32;
  const int lx = threadIdx.x & 31, ly = threadIdx.x >> 5;
#pragma unroll
  for (int i = 0; i < 32; i += 8)
    tile[ly + i][lx] = f2bf(in[(size_t)(br + ly + i) * C + bc + lx]);
  __syncthreads();
#pragma unroll
  for (int i = 0; i < 32; i += 8)
    out[(size_t)(bc + ly + i) * R + br + lx] = tile[lx][ly + i];
}

// bf16 -> bf16 transpose (for V inside QKV).
__global__ __launch_bounds__(256) void transpose_b(
    const bf16u* __restrict__ in, bf16u* __restrict__ out,
    int ins, int coff, int outs) {
  __shared__ bf16u tile[32][33];
  const int bc = blockIdx.x * 32, br = blockIdx.y * 32;
  const int lx = threadIdx.x & 31, ly = threadIdx.x >> 5;
#pragma unroll
  for (int i = 0; i < 32; i += 8)
    tile[ly + i][lx] = in[(size_t)(br + ly + i) * ins + coff + bc + lx];
  __syncthreads();
#pragma unroll
  for (int i = 0; i < 32; i += 8)
    out[(size_t)(bc + ly + i) * outs + br + lx] = tile[lx][ly + i];
}

// ---------------------------------------------------------------- GEMM (B^T)
// XOR-swizzled LDS; min 4 blocks/CU (round-11 lesson: the old (256,2) bound
// for BN=128 self-capped QKV/FFN1 at half their possible residency).
template <int BM, int BN, int WGR, int WGC, int EPI>
__global__ __launch_bounds__(256, 4) void gemm_bt(
    const bf16u* __restrict__ A, const bf16u* __restrict__ Bt,
    const float* __restrict__ bias, const float* __restrict__ res,
    void* __restrict__ Cout, int M, int N, int K, int kchunk) {
  constexpr int BK = 64;
  constexpr int TM = BM / WGR, TN = BN / WGC;
  constexpr int NI = TM / 16, NJ = TN / 16;
  alignas(16) __shared__ bf16u sA[BM * BK];
  alignas(16) __shared__ bf16u sB[BN * BK];
  const int tid = threadIdx.x, lane = tid & 63, wave = tid >> 6;
  const int wr = wave / WGC, wc = wave % WGC;
  const int quad = lane >> 4, l16 = lane & 15;
  const int m0 = blockIdx.y * BM, n0 = blockIdx.x * BN;
  const int kz = blockIdx.z;
  const int kbeg = kz * kchunk;
  const int kend = (kbeg + kchunk < K) ? (kbeg + kchunk) : K;

  floatx4 acc[NI][NJ] = {};
  constexpr int ACH = BM * BK / 8;
  constexpr int BCH = BN * BK / 8;

  for (int k0 = kbeg; k0 < kend; k0 += BK) {
#pragma unroll
    for (int c = tid; c < ACH; c += 256) {
      int r = c >> 3, kc = ((c ^ r) & 7) * 8;  // swizzled source chunk
      load_lds16(A + (size_t)(m0 + r) * K + k0 + kc, (void*)(sA + c * 8));
    }
#pragma unroll
    for (int c = tid; c < BCH; c += 256) {
      int r = c >> 3, kc = ((c ^ r) & 7) * 8;
      load_lds16(Bt + (size_t)(n0 + r) * K + k0 + kc, (void*)(sB + c * 8));
    }
    __syncthreads();
#pragma unroll
    for (int kk = 0; kk < BK; kk += 32) {
      const int ch = (kk >> 3) + quad;
      short8 af[NI], bf[NJ];
#pragma unroll
      for (int i = 0; i < NI; i++) {
        const int R = wr * TM + i * 16 + l16;
        af[i] = *(const short8*)(sA + R * BK + ((ch ^ (R & 7)) << 3));
      }
#pragma unroll
      for (int j = 0; j < NJ; j++) {
        const int R = wc * TN + j * 16 + l16;
        bf[j] = *(const short8*)(sB + R * BK + ((ch ^ (R & 7)) << 3));
      }
#pragma unroll
      for (int i = 0; i < NI; i++)
#pragma unroll
        for (int j = 0; j < NJ; j++)
          acc[i][j] = __builtin_amdgcn_mfma_f32_16x16x32_bf16(af[i], bf[j], acc[i][j], 0, 0, 0);
    }
    __syncthreads();
  }

  float* pout = (float*)Cout;
  if constexpr (EPI == 3) pout += (size_t)kz * M * N;
#pragma unroll
  for (int j = 0; j < NJ; j++) {
    const int col = n0 + wc * TN + j * 16 + l16;
    float bv = 0.0f;
    if constexpr (EPI == 1 || EPI == 2) bv = bias[col];
#pragma unroll
    for (int i = 0; i < NI; i++) {
#pragma unroll
      for (int r = 0; r < 4; r++) {
        const int row = m0 + wr * TM + i * 16 + quad * 4 + r;
        const size_t o = (size_t)row * N + col;
        const float v = acc[i][j][r];
        if constexpr (EPI == 0) {
          ((bf16u*)Cout)[o] = f2bf(v);
        } else if constexpr (EPI == 1) {
          pout[o] = v + bv + res[o];
        } else if constexpr (EPI == 2) {
          float t = v + bv;
          ((bf16u*)Cout)[o] = f2bf(0.5f * t * (1.0f + erff(t * 0.70710678118654752f)));
        } else {
          pout[o] = v;
        }
      }
    }
  }
}

// ---------------------------------------------------------------- split-K reduce (FFN2)
__global__ __launch_bounds__(256) void reduce2_kernel(
    const float* __restrict__ part, const float* __restrict__ bias,
    const float* __restrict__ res, float* __restrict__ out,
    int N, size_t total) {
  size_t i = ((size_t)blockIdx.x * 256 + threadIdx.x) * 4;
  if (i >= total) return;
  float4 a = *(const float4*)(part + i);
  float4 b = *(const float4*)(part + total + i);
  float4 r = *(const float4*)(res + i);
  float4 bv = *(const float4*)(bias + (int)(i & (size_t)(N - 1)));
  float4 o;
  o.x = a.x + b.x + r.x + bv.x;
  o.y = a.y + b.y + r.y + bv.y;
  o.z = a.z + b.z + r.z + bv.z;
  o.w = a.w + b.w + r.w + bv.w;
  *(float4*)(out + i) = o;
}

// ---------------------------------------------------------------- Flash attention v2
// Fixed-max softmax + split-K over key tiles (round 11). v2: UNPADDED
// XOR-swizzled LDS (chunk c of row r at slot c^(r&7)) — kills the 8-way
// V-staging write conflict the padded layout had, and shrinks LDS 45->40KB
// so 4 blocks/CU fit. MASK template: only diagonal tiles pay the causal
// cmp/cndmask.
template <int NT, bool MASK>
__device__ __forceinline__ void attn_tile(
    const bf16u* sQ, const bf16u* sK, const bf16u* sVt, bf16u* sP,
    floatx4* aco, floatx4& acc_l, short8 ones,
    int q0, int c0, int wave, int quad, int l16) {
  const int rq = wave * 16 + l16;
  floatx4 s[NT] = {};
#pragma unroll
  for (int kk = 0; kk < 64; kk += 32) {
    const int ch = (kk >> 3) + quad;
    short8 aq = *(const short8*)(sQ + rq * 64 + ((ch ^ (rq & 7)) << 3));
#pragma unroll
    for (int nt = 0; nt < NT; nt++) {
      const int rk = nt * 16 + l16;
      short8 bk = *(const short8*)(sK + rk * 64 + ((ch ^ (rk & 7)) << 3));
      s[nt] = __builtin_amdgcn_mfma_f32_16x16x32_bf16(bk, aq, s[nt], 0, 0, 0);
    }
  }
  const float C = 0.125f * 1.44269504088896f;  // 1/sqrt(64) * log2(e)
  const int qrow = q0 + rq;
#pragma unroll
  for (int nt = 0; nt < NT; nt++)
#pragma unroll
    for (int r = 0; r < 4; r++) {
      float t = s[nt][r] * C;
      if constexpr (MASK) {
        const int kpos = c0 + nt * 16 + quad * 4 + r;
        if (kpos > qrow) t = -__builtin_inff();
      }
      s[nt][r] = __builtin_amdgcn_exp2f(t);
    }
  __syncthreads();  // all waves done reading sK before sP overwrite
#pragma unroll
  for (int nt = 0; nt < NT; nt++) {
    unsigned int lo = (unsigned int)f2bf(s[nt][0]) | ((unsigned int)f2bf(s[nt][1]) << 16);
    unsigned int hi = (unsigned int)f2bf(s[nt][2]) | ((unsigned int)f2bf(s[nt][3]) << 16);
    uint2 pk; pk.x = lo; pk.y = hi;
    const int e0 = nt * 16 + quad * 4;
    const int cch = e0 >> 3, sub = e0 & 7;
    *(uint2*)(sP + rq * 128 + ((cch ^ (rq & 7)) << 3) + sub) = pk;
  }
  __syncthreads();  // sP fully written
#pragma unroll
  for (int kk = 0; kk < NT * 16; kk += 32) {
    const int ch = (kk >> 3) + quad;
    short8 ap = *(const short8*)(sP + rq * 128 + ((ch ^ (rq & 7)) << 3));
#pragma unroll
    for (int dt = 0; dt < 4; dt++) {
      const int rv = dt * 16 + l16;
      short8 bv = *(const short8*)(sVt + rv * 128 + ((ch ^ (rv & 7)) << 3));
      aco[dt] = __builtin_amdgcn_mfma_f32_16x16x32_bf16(ap, bv, aco[dt], 0, 0, 0);
    }
    acc_l = __builtin_amdgcn_mfma_f32_16x16x32_bf16(ap, ones, acc_l, 0, 0, 0);
  }
}

template <int NZ>
__global__ __launch_bounds__(256, 4) void flash_attn(
    const bf16u* __restrict__ QKV, const bf16u* __restrict__ Vt,
    bf16u* __restrict__ partO, float* __restrict__ partL) {
  const int qb = 31 - blockIdx.x;
  const int h = blockIdx.y;
  const int z = blockIdx.z;
  const int tid = threadIdx.x, lane = tid & 63, wave = tid >> 6;
  const int quad = lane >> 4, l16 = lane & 15;
  alignas(16) __shared__ bf16u sQ[64 * 64];    //  8 KB
  alignas(16) __shared__ bf16u sK[128 * 64];   // 16 KB, overlaid by sP (64x128)
  alignas(16) __shared__ bf16u sVt[64 * 128];  // 16 KB
  bf16u* sP = sK;
  const int q0 = qb * 64;

  for (int c = tid; c < 512; c += 256) {
    int r = c >> 3, cc = c & 7;
    *(uint4*)(sQ + r * 64 + ((cc ^ (r & 7)) << 3)) =
        *(const uint4*)(QKV + (size_t)(q0 + r) * 3072 + h * 64 + cc * 8);
  }

  floatx4 acc_l = {0.f, 0.f, 0.f, 0.f};
  floatx4 aco[4] = {};
  short8 ones;
#pragma unroll
  for (int u = 0; u < 8; u++) ones[u] = (short)0x3F80;  // bf16 1.0

  const int nkt = (qb >> 1) + 1;  // 128-wide K tiles
  for (int kt = z; kt < nkt; kt += NZ) {
    const int c0 = kt * 128;
    __syncthreads();
    for (int c = tid; c < 1024; c += 256) {
      int r = c >> 3, cc = c & 7;
      *(uint4*)(sK + r * 64 + ((cc ^ (r & 7)) << 3)) =
          *(const uint4*)(QKV + (size_t)(c0 + r) * 3072 + 1024 + h * 64 + cc * 8);
    }
    for (int c = tid; c < 1024; c += 256) {
      int e = c >> 4, cc = c & 15;
      *(uint4*)(sVt + e * 128 + ((cc ^ (e & 7)) << 3)) =
          *(const uint4*)(Vt + (size_t)(h * 64 + e) * 2048 + c0 + cc * 8);
    }
    __syncthreads();
    if (kt == nkt - 1) {
      if ((qb & 1) == 0)
        attn_tile<4, true>(sQ, sK, sVt, sP, aco, acc_l, ones, q0, c0, wave, quad, l16);
      else
        attn_tile<8, true>(sQ, sK, sVt, sP, aco, acc_l, ones, q0, c0, wave, quad, l16);
    } else {
      attn_tile<8, false>(sQ, sK, sVt, sP, aco, acc_l, ones, q0, c0, wave, quad, l16);
    }
  }
  // write partials (zero-iteration blocks write zeros — every slot covered once)
  bf16u* po = partO + ((size_t)z * 2048 + q0) * 1024 + h * 64;
#pragma unroll
  for (int dt = 0; dt < 4; dt++)
#pragma unroll
    for (int r = 0; r < 4; r++)
      po[(wave * 16 + quad * 4 + r) * 1024 + dt * 16 + l16] = f2bf(aco[dt][r]);
  if (l16 == 0) {
#pragma unroll
    for (int r = 0; r < 4; r++)
      partL[((size_t)z * 2048 + q0 + wave * 16 + quad * 4 + r) * 16 + h] = acc_l[r];
  }
}

// combine: ctx[t][col] = sum_z O_z / sum_z l_z
template <int NZ>
__global__ __launch_bounds__(256) void attn_reduce(
    const bf16u* __restrict__ partO, const float* __restrict__ partL,
    bf16u* __restrict__ ctx) {
  const int t = blockIdx.x;
  const int col = threadIdx.x * 4;
  const int h = col >> 6;
  float l = 0.f;
#pragma unroll
  for (int z = 0; z < NZ; z++) l += partL[((size_t)z * 2048 + t) * 16 + h];
  float o0 = 0.f, o1 = 0.f, o2 = 0.f, o3 = 0.f;
#pragma unroll
  for (int z = 0; z < NZ; z++) {
    uint2 v = *(const uint2*)(partO + ((size_t)z * 2048 + t) * 1024 + col);
    o0 += bf2f((bf16u)(v.x & 0xffff)); o1 += bf2f((bf16u)(v.x >> 16));
    o2 += bf2f((bf16u)(v.y & 0xffff)); o3 += bf2f((bf16u)(v.y >> 16));
  }
  const float inv = 1.0f / l;
  uint2 pk;
  pk.x = (unsigned int)f2bf(o0 * inv) | ((unsigned int)f2bf(o1 * inv) << 16);
  pk.y = (unsigned int)f2bf(o2 * inv) | ((unsigned int)f2bf(o3 * inv) << 16);
  *(uint2*)(ctx + (size_t)t * 1024 + col) = pk;
}

// ---------------------------------------------------------------- launch
extern "C" void kernel_launch(void* const* d_in, const int* in_sizes, int n_in,
                              void* d_out, int out_size, void* d_ws, size_t ws_size,
                              hipStream_t stream) {
  (void)in_sizes; (void)n_in; (void)out_size; (void)ws_size;
  const float* x   = (const float*)d_in[0];
  const float* wq  = (const float*)d_in[1];
  const float* wk  = (const float*)d_in[2];
  const float* wv  = (const float*)d_in[3];
  const float* wo  = (const float*)d_in[4];
  const float* bo  = (const float*)d_in[5];
  const float* g1  = (const float*)d_in[6];
  const float* be1 = (const float*)d_in[7];
  const float* g2  = (const float*)d_in[8];
  const float* be2 = (const float*)d_in[9];
  const float* w1  = (const float*)d_in[10];
  const float* bb1 = (const float*)d_in[11];
  const float* w2  = (const float*)d_in[12];
  const float* bb2 = (const float*)d_in[13];

  char* p = (char*)d_ws;
  const size_t MB = 1024 * 1024;
  constexpr int NZ = 4;
  bf16u* WqkvT = (bf16u*)(p + 0 * MB);
  bf16u* woT   = (bf16u*)(p + 6 * MB);
  bf16u* w1T   = (bf16u*)(p + 8 * MB);
  bf16u* w2T   = (bf16u*)(p + 16 * MB);
  bf16u* multi = (bf16u*)(p + 24 * MB);   // hln / Vtr / ctx / h2
  bf16u* QKV   = (bf16u*)(p + 28 * MB);
  float* partL = (float*)(p + 40 * MB);
  bf16u* partO = (bf16u*)(p + 41 * MB);
  bf16u* mid   = (bf16u*)(p + 28 * MB);
  float* x1    = (float*)(p + 49 * MB);
  float* partF = (float*)(p + 0 * MB);
  bf16u* hln = multi, *Vtr = multi, *ctx = multi, *h2 = multi;

  pack_weights<<<12288, 256, 0, stream>>>(wq, wk, wv, wo, w1, w2,
                                          WqkvT, woT, w1T, w2T);

  // h = LN1(x); QKV = h @ [wq|wk|wv]
  ln_kernel<<<2048, 256, 0, stream>>>(x, hln, g1, be1);
  gemm_bt<64, 128, 2, 2, 0><<<dim3(24, 32, 1), 256, 0, stream>>>(
      hln, WqkvT, nullptr, nullptr, QKV, 2048, 3072, 1024, 1024);
  // Vtr[c][t] = V[t][c]
  transpose_b<<<dim3(32, 64), 256, 0, stream>>>(QKV, Vtr, 3072, 2048, 2048);
  // split-K flash attention (2048 balanced blocks) + combine
  flash_attn<NZ><<<dim3(32, 16, NZ), 256, 0, stream>>>(QKV, Vtr, partO, partL);
  attn_reduce<NZ><<<2048, 256, 0, stream>>>(partO, partL, ctx);
  // x1 = x + ctx @ wo + bo (fp32)
  gemm_bt<32, 64, 2, 2, 1><<<dim3(16, 64, 1), 256, 0, stream>>>(
      ctx, woT, bo, x, x1, 2048, 1024, 1024, 1024);
  // h2 = LN2(x1); mid = gelu(h2 @ w1 + b1)
  ln_kernel<<<2048, 256, 0, stream>>>(x1, h2, g2, be2);
  gemm_bt<64, 128, 2, 2, 2><<<dim3(32, 32, 1), 256, 0, stream>>>(
      h2, w1T, bb1, nullptr, mid, 2048, 4096, 1024, 1024);
  // out = x1 + mid @ w2 + b2 : split-K=2 + fused reduce
  gemm_bt<64, 64, 2, 2, 3><<<dim3(16, 32, 2), 256, 0, stream>>>(
      mid, w2T, nullptr, nullptr, partF, 2048, 1024, 4096, 2048);
  reduce2_kernel<<<2048, 256, 0, stream>>>(partF, bb2, x1, (float*)d_out,
                                           1024, (size_t)2048 * 1024);
}